// Round 6
// baseline (439.948 us; speedup 1.0000x reference)
//
#include <hip/hip_runtime.h>

#define NE 8
#define NTOK 8192
#define DIN 2048
#define DOUT 4096

// ---- 256x256, BK=64, 8 waves, 2 phases/K-tile; A via gload_lds(bf16),
// ---- B reg-staged fp32 -> cvt -> ds_write (kills the W-cvt pass) ----
#define BM 256
#define BN 256
#define BK 64
#define NTN (DOUT / BN)          // 16 n-tiles
#define MAXMT (NTOK / BM + NE)   // 40 worst-case m-tiles -> 640 blocks (%8==0)
#define NKT (DIN / BK)           // 32 K-tiles
#define LDS_BUF 65536            // one buffer: A 32K + B 32K
#define BOFF 32768               // B offset inside a buffer
#define GRAN 8192                // A granule = 64 rows x 64 cols x 2B

typedef __attribute__((ext_vector_type(4))) float f32x4;
typedef __attribute__((ext_vector_type(8))) short short8;
typedef __attribute__((ext_vector_type(8))) __bf16 bf16x8;

__device__ __forceinline__ void gload_lds16(const void* g, void* l) {
  __builtin_amdgcn_global_load_lds(
      (const __attribute__((address_space(1))) void*)g,
      (__attribute__((address_space(3))) void*)l,
      16, 0, 0);
}

// ---------------- fp32 -> bf16 conversion pass (x only now, ~16 us) ----------------
__global__ void cvt_f32_bf16(const float* __restrict__ in,
                             __bf16* __restrict__ out, int n8) {
  const int stride = gridDim.x * blockDim.x;
  for (int i = blockIdx.x * blockDim.x + threadIdx.x; i < n8; i += stride) {
    const f32x4* p = reinterpret_cast<const f32x4*>(in + (size_t)i * 8);
    f32x4 a = p[0], b = p[1];
    bf16x8 v;
    v[0] = (__bf16)a[0]; v[1] = (__bf16)a[1];
    v[2] = (__bf16)a[2]; v[3] = (__bf16)a[3];
    v[4] = (__bf16)b[0]; v[5] = (__bf16)b[1];
    v[6] = (__bf16)b[2]; v[7] = (__bf16)b[3];
    *reinterpret_cast<bf16x8*>(out + (size_t)i * 8) = v;
  }
}

__device__ __forceinline__ bf16x8 lds_rd(const char* p) {
  return *reinterpret_cast<const bf16x8*>(p);
}

__device__ __forceinline__ f32x4 mfma16(bf16x8 a, bf16x8 b, f32x4 c) {
  return __builtin_amdgcn_mfma_f32_16x16x32_bf16(
      __builtin_bit_cast(short8, a), __builtin_bit_cast(short8, b), c, 0, 0, 0);
}

// R3-verified swizzle (measured 0 conflicts): row r, byte-col cb:
//   byte = r*128 + (cb ^ ((r&7)<<4))
__device__ __forceinline__ int lds_off(int r, int cb) {
  return r * 128 + (cb ^ ((r & 7) << 4));
}

__device__ __forceinline__ bf16x8 pack_bf16(f32x4 a, f32x4 b) {
  bf16x8 v;
  v[0] = (__bf16)a[0]; v[1] = (__bf16)a[1];
  v[2] = (__bf16)a[2]; v[3] = (__bf16)a[3];
  v[4] = (__bf16)b[0]; v[5] = (__bf16)b[1];
  v[6] = (__bf16)b[2]; v[7] = (__bf16)b[3];
  return v;
}

// ---------------- grouped GEMM: A bf16 gload_lds, B fp32 fused-cvt ----------------
__global__ __launch_bounds__(512, 2)
void moe_gemm_fusedW(const __bf16* __restrict__ xb,
                     const float* __restrict__ w,
                     const int* __restrict__ ef,
                     float* __restrict__ out) {
  __shared__ __attribute__((aligned(16))) char lds[2 * LDS_BUF];  // 128 KiB

  const int tid  = threadIdx.x;
  const int lane = tid & 63;
  const int wv   = tid >> 6;   // 0..7
  const int wm   = wv >> 2;    // 0..1 (M split, 128 rows)
  const int wn   = wv & 3;     // 0..3 (N split, 64 cols)
  const int fr   = lane & 15;
  const int kg   = lane >> 4;

  // T1: bijective XCD swizzle (640 % 8 == 0); nt fastest within chunk
  const int b    = blockIdx.x;
  const int tile = (b & 7) * (MAXMT * NTN / 8) + (b >> 3);
  const int nt   = tile % NTN;
  const int mt   = tile / NTN;

  // m-tile -> (expert, row range); tokens contiguous per expert
  int cumT = 0, cumTok = 0;
  int e = -1, rowStart = 0, lastRow = 0;
  for (int i = 0; i < NE; ++i) {
    int f = ef[i];
    int t = (f + BM - 1) / BM;
    if (mt < cumT + t) {
      e = i;
      rowStart = cumTok + (mt - cumT) * BM;
      lastRow  = cumTok + f - 1;
      break;
    }
    cumT += t;
    cumTok += f;
  }
  if (e < 0) return;  // dead tile, uniform across block, before any barrier

  const float* wexp = w + (size_t)e * DOUT * DIN;
  const int ncol0 = nt * BN;

  // ---- A staging (R3-verified): granule g = 64 rows; wave covers rows
  // g*64 + wv*8 .. +7; source slot pre-applies the read involution.
  const int srow  = wv * 8 + (lane >> 3);
  const int sslot = (lane & 7) ^ (lane >> 3);
  const __bf16* aSrc[4];
#pragma unroll
  for (int j = 0; j < 4; ++j) {
    int ar = rowStart + j * 64 + srow;
    ar = ar > lastRow ? lastRow : ar;          // clamp ragged M (C guarded)
    aSrc[j] = xb + (size_t)ar * DIN + sslot * 8;
  }

  // ---- B reg-staging geometry: idx covers row r = idx>>1 (0..255),
  // k-half kh = idx&1 (32 floats = 128B contiguous per lane).
  const int brow = tid >> 1;                   // W row (DOUT dim) within panel
  const int kh   = tid & 1;
  const float* bSrc = wexp + (size_t)(ncol0 + brow) * DIN + kh * 32;
  // ds_write targets: write w covers bf16 elems kh*32 + w*8 .. +7
  char* bDstBase = lds + BOFF;
  int bWrOff[4];
#pragma unroll
  for (int q = 0; q < 4; ++q)
    bWrOff[q] = lds_off(brow, (kh * 32 + q * 8) * 2);

#define STA(bufi, j, k0) gload_lds16(aSrc[j] + (k0), lds + (bufi)*LDS_BUF + (j)*GRAN + wv*1024)
#define LDA(bufi, r, cb) lds_rd(lds + (bufi)*LDS_BUF + lds_off((r), (cb)))
#define LDB(bufi, r, cb) lds_rd(lds + (bufi)*LDS_BUF + BOFF + lds_off((r), (cb)))

  f32x4 acc[8][4];
#pragma unroll
  for (int m = 0; m < 8; ++m)
#pragma unroll
    for (int n = 0; n < 4; ++n)
      acc[m][n] = f32x4{0.f, 0.f, 0.f, 0.f};

  f32x4 br[8];

  // ---- prologue ----
#pragma unroll
  for (int q = 0; q < 8; ++q)   // B(0) fp32 regs, k0 = 0
    br[q] = *reinterpret_cast<const f32x4*>(bSrc + q * 4);
  STA(0, 0, 0); STA(0, 1, 0); STA(0, 2, 0); STA(0, 3, 0);   // A(0)
  STA(1, 0, BK); STA(1, 2, BK);                              // A(1) g0,g2
  {  // cvt + write B(0) -> buf0 (compiler auto-waits the br loads)
    char* d = bDstBase + 0 * LDS_BUF;
#pragma unroll
    for (int q = 0; q < 4; ++q)
      *reinterpret_cast<bf16x8*>(d + bWrOff[q]) = pack_bf16(br[2 * q], br[2 * q + 1]);
  }
  asm volatile("s_waitcnt lgkmcnt(0)" ::: "memory");  // B writes drained
  asm volatile("s_waitcnt vmcnt(2)" ::: "memory");    // A(0) landed; A(1) g0,g2 fly
  __builtin_amdgcn_s_barrier();

  for (int t = 0; t < NKT; ++t) {
    const int buf = t & 1;
    bf16x8 bfr[2][4];

    // ================= phase 0: acc rows 0..3 (A granule 2*wm) =================
    if (t + 1 < NKT) {
#pragma unroll
      for (int q = 0; q < 8; ++q)   // issue B(t+1) fp32 loads (consumed at P1)
        br[q] = *reinterpret_cast<const f32x4*>(bSrc + (size_t)(t + 1) * BK + q * 4);
      STA(buf ^ 1, 1, (t + 1) * BK);  // A(t+1) g1,g3 (region read at t-1 P1, drained)
      STA(buf ^ 1, 3, (t + 1) * BK);
    }
    {
      bf16x8 a0[2][4];
#pragma unroll
      for (int kk = 0; kk < 2; ++kk) {
#pragma unroll
        for (int nn = 0; nn < 4; ++nn)
          bfr[kk][nn] = LDB(buf, wn * 64 + nn * 16 + fr, kk * 64 + kg * 16);
#pragma unroll
        for (int i = 0; i < 4; ++i)
          a0[kk][i] = LDA(buf, wm * 128 + i * 16 + fr, kk * 64 + kg * 16);
      }
      __builtin_amdgcn_s_barrier();
      asm volatile("s_waitcnt lgkmcnt(0)" ::: "memory");
      __builtin_amdgcn_s_setprio(1);
#pragma unroll
      for (int kk = 0; kk < 2; ++kk)
#pragma unroll
        for (int i = 0; i < 4; ++i)
#pragma unroll
          for (int nn = 0; nn < 4; ++nn)
            acc[i][nn] = mfma16(a0[kk][i], bfr[kk][nn], acc[i][nn]);
      __builtin_amdgcn_s_setprio(0);
      __builtin_amdgcn_s_barrier();
    }

    // ================= phase 1: acc rows 4..7 (A granule 2*wm+1) =================
    {
      if (t + 2 < NKT) {            // A(t+2) g0,g2 (granules consumed at P0)
        STA(buf, 0, (t + 2) * BK);
        STA(buf, 2, (t + 2) * BK);
      }
      if (t + 1 < NKT) {            // cvt + write B(t+1) -> buf^1 (auto-wait br)
        char* d = bDstBase + (buf ^ 1) * LDS_BUF;
#pragma unroll
        for (int q = 0; q < 4; ++q)
          *reinterpret_cast<bf16x8*>(d + bWrOff[q]) = pack_bf16(br[2 * q], br[2 * q + 1]);
      }
      bf16x8 a1[2][4];
#pragma unroll
      for (int kk = 0; kk < 2; ++kk)
#pragma unroll
        for (int i = 0; i < 4; ++i)
          a1[kk][i] = LDA(buf, wm * 128 + (4 + i) * 16 + fr, kk * 64 + kg * 16);
      __builtin_amdgcn_s_barrier();
      asm volatile("s_waitcnt lgkmcnt(0)" ::: "memory");  // reads + B writes drained
      __builtin_amdgcn_s_setprio(1);
#pragma unroll
      for (int kk = 0; kk < 2; ++kk)
#pragma unroll
        for (int i = 0; i < 4; ++i)
#pragma unroll
          for (int nn = 0; nn < 4; ++nn)
            acc[4 + i][nn] = mfma16(a1[kk][i], bfr[kk][nn], acc[4 + i][nn]);
      __builtin_amdgcn_s_setprio(0);
      // counted vmcnt (T4): A(t+1) g1,g3 must land; keep A(t+2) g0,g2 in flight
      if (t + 1 < NKT) {
        if (t + 2 < NKT) { asm volatile("s_waitcnt vmcnt(2)" ::: "memory"); }
        else             { asm volatile("s_waitcnt vmcnt(0)" ::: "memory"); }
      }
      __builtin_amdgcn_s_barrier();
    }
  }

  // ---- epilogue: C/D layout col = lane&15, row = (lane>>4)*4 + j ----
  const int rq = (lane >> 4) * 4;
#pragma unroll
  for (int mm = 0; mm < 8; ++mm) {
#pragma unroll
    for (int j = 0; j < 4; ++j) {
      const int grow = rowStart + wm * 128 + mm * 16 + rq + j;
      if (grow <= lastRow) {
        float* op = out + (size_t)grow * DOUT + ncol0 + wn * 64;
#pragma unroll
        for (int nn = 0; nn < 4; ++nn)
          op[nn * 16 + fr] = acc[mm][nn][j];
      }
    }
  }
#undef STA
#undef LDA
#undef LDB
}

// ---------------- fallback: fused fp32-staging kernel (R1, verified) ----------------
__device__ __forceinline__ short8 cvt_bf16x8(f32x4 a, f32x4 b) {
  bf16x8 v;
  v[0] = (__bf16)a[0]; v[1] = (__bf16)a[1];
  v[2] = (__bf16)a[2]; v[3] = (__bf16)a[3];
  v[4] = (__bf16)b[0]; v[5] = (__bf16)b[1];
  v[6] = (__bf16)b[2]; v[7] = (__bf16)b[3];
  return __builtin_bit_cast(short8, v);
}

__global__ __launch_bounds__(256, 2)
void moe_grouped_gemm_f32(const float* __restrict__ x,
                          const float* __restrict__ w,
                          const int* __restrict__ ef,
                          float* __restrict__ out) {
  __shared__ float As[128 * 32];
  __shared__ float Bs[128 * 32];
  const int tid = threadIdx.x, lane = tid & 63, wv = tid >> 6;
  const int bid = blockIdx.x, nt = bid % 32, mt = bid / 32;
  int cumT = 0, cumTok = 0, e = -1, rowStart = 0, lastRow = 0;
  for (int i = 0; i < NE; ++i) {
    int f = ef[i], t = (f + 127) / 128;
    if (mt < cumT + t) { e = i; rowStart = cumTok + (mt - cumT) * 128; lastRow = cumTok + f - 1; break; }
    cumT += t; cumTok += f;
  }
  if (e < 0) return;
  const float* wexp = w + (size_t)e * DOUT * DIN;
  const int ncol0 = nt * 128;
  const int srow = lane >> 3, scol = (lane & 7) * 4;
  f32x4 acc[4][4];
#pragma unroll
  for (int m = 0; m < 4; ++m)
#pragma unroll
    for (int n = 0; n < 4; ++n) acc[m][n] = f32x4{0.f, 0.f, 0.f, 0.f};
  const int wr = (wv >> 1) * 64, wc = (wv & 1) * 64;
  for (int k0 = 0; k0 < DIN; k0 += 32) {
    __syncthreads();
#pragma unroll
    for (int i = 0; i < 4; ++i) {
      const int seg = i * 4 + wv;
      int arow = rowStart + seg * 8 + srow;
      arow = arow > lastRow ? lastRow : arow;
      gload_lds16(x + (size_t)arow * DIN + k0 + scol, &As[seg * 256]);
      const int brow = ncol0 + seg * 8 + srow;
      gload_lds16(wexp + (size_t)brow * DIN + k0 + scol, &Bs[seg * 256]);
    }
    __syncthreads();
    const int kb = (lane >> 4) * 8, fr = lane & 15;
    short8 afr[4], bfr[4];
#pragma unroll
    for (int m = 0; m < 4; ++m) {
      const f32x4* p = reinterpret_cast<const f32x4*>(&As[(wr + m * 16 + fr) * 32 + kb]);
      afr[m] = cvt_bf16x8(p[0], p[1]);
    }
#pragma unroll
    for (int n = 0; n < 4; ++n) {
      const f32x4* p = reinterpret_cast<const f32x4*>(&Bs[(wc + n * 16 + fr) * 32 + kb]);
      bfr[n] = cvt_bf16x8(p[0], p[1]);
    }
#pragma unroll
    for (int m = 0; m < 4; ++m)
#pragma unroll
      for (int n = 0; n < 4; ++n)
        acc[m][n] = __builtin_amdgcn_mfma_f32_16x16x32_bf16(afr[m], bfr[n], acc[m][n], 0, 0, 0);
  }
  const int fr = lane & 15, rq = (lane >> 4) * 4;
#pragma unroll
  for (int m = 0; m < 4; ++m)
#pragma unroll
    for (int j = 0; j < 4; ++j) {
      const int grow = rowStart + wr + m * 16 + rq + j;
      if (grow <= lastRow) {
        float* op = out + (size_t)grow * DOUT + ncol0 + wc;
#pragma unroll
        for (int n = 0; n < 4; ++n) op[n * 16 + fr] = acc[m][n][j];
      }
    }
}

extern "C" void kernel_launch(void* const* d_in, const int* in_sizes, int n_in,
                              void* d_out, int out_size, void* d_ws, size_t ws_size,
                              hipStream_t stream) {
  const float* x  = (const float*)d_in[0];
  const float* w  = (const float*)d_in[1];
  const int*   ef = (const int*)d_in[2];
  float* out = (float*)d_out;
  (void)in_sizes; (void)n_in; (void)out_size;

  const size_t nx = (size_t)NTOK * DIN;            // 16.8M elems
  const size_t need = nx * sizeof(__bf16);         // 32 MiB (x only)

  if (ws_size >= need) {
    __bf16* xb = (__bf16*)d_ws;
    {
      int n8 = (int)(nx / 8);
      int grid = (n8 + 255) / 256; if (grid > 2048) grid = 2048;
      cvt_f32_bf16<<<dim3(grid), dim3(256), 0, stream>>>(x, xb, n8);
    }
    moe_gemm_fusedW<<<dim3(MAXMT * NTN), dim3(512), 0, stream>>>(xb, w, ef, out);
  } else {
    moe_grouped_gemm_f32<<<dim3((NTOK / 128 + NE) * 32), dim3(256), 0, stream>>>(x, w, ef, out);
  }
}

// Round 7
// 380.142 us; speedup vs baseline: 1.1573x; 1.1573x over previous
//
#include <hip/hip_runtime.h>

#define NE 8
#define NTOK 8192
#define DIN 2048
#define DOUT 4096

// ---- 256x256, BK=64, 8 waves, 2 phases/K-tile; A via gload_lds(bf16),
// ---- B reg-staged fp32 -> cvt -> ds_write, issue-at-P1 (1 K-tile latency cover)
#define BM 256
#define BN 256
#define BK 64
#define NTN (DOUT / BN)          // 16 n-tiles
#define MAXMT (NTOK / BM + NE)   // 40 worst-case m-tiles -> 640 blocks (%8==0)
#define NKT (DIN / BK)           // 32 K-tiles
#define LDS_BUF 65536            // one buffer: A 32K + B 32K
#define BOFF 32768               // B offset inside a buffer
#define GRAN 8192                // A granule = 64 rows x 64 cols x 2B

typedef __attribute__((ext_vector_type(4))) float f32x4;
typedef __attribute__((ext_vector_type(8))) short short8;
typedef __attribute__((ext_vector_type(8))) __bf16 bf16x8;

__device__ __forceinline__ void gload_lds16(const void* g, void* l) {
  __builtin_amdgcn_global_load_lds(
      (const __attribute__((address_space(1))) void*)g,
      (__attribute__((address_space(3))) void*)l,
      16, 0, 0);
}

// ---------------- fp32 -> bf16 conversion pass (x only, ~16 us) ----------------
__global__ void cvt_f32_bf16(const float* __restrict__ in,
                             __bf16* __restrict__ out, int n8) {
  const int stride = gridDim.x * blockDim.x;
  for (int i = blockIdx.x * blockDim.x + threadIdx.x; i < n8; i += stride) {
    const f32x4* p = reinterpret_cast<const f32x4*>(in + (size_t)i * 8);
    f32x4 a = p[0], b = p[1];
    bf16x8 v;
    v[0] = (__bf16)a[0]; v[1] = (__bf16)a[1];
    v[2] = (__bf16)a[2]; v[3] = (__bf16)a[3];
    v[4] = (__bf16)b[0]; v[5] = (__bf16)b[1];
    v[6] = (__bf16)b[2]; v[7] = (__bf16)b[3];
    *reinterpret_cast<bf16x8*>(out + (size_t)i * 8) = v;
  }
}

__device__ __forceinline__ bf16x8 lds_rd(const char* p) {
  return *reinterpret_cast<const bf16x8*>(p);
}

__device__ __forceinline__ f32x4 mfma16(bf16x8 a, bf16x8 b, f32x4 c) {
  return __builtin_amdgcn_mfma_f32_16x16x32_bf16(
      __builtin_bit_cast(short8, a), __builtin_bit_cast(short8, b), c, 0, 0, 0);
}

// R3-verified swizzle (measured 0 conflicts): row r, byte-col cb:
//   byte = r*128 + (cb ^ ((r&7)<<4))
__device__ __forceinline__ int lds_off(int r, int cb) {
  return r * 128 + (cb ^ ((r & 7) << 4));
}

__device__ __forceinline__ bf16x8 pack_bf16(f32x4 a, f32x4 b) {
  bf16x8 v;
  v[0] = (__bf16)a[0]; v[1] = (__bf16)a[1];
  v[2] = (__bf16)a[2]; v[3] = (__bf16)a[3];
  v[4] = (__bf16)b[0]; v[5] = (__bf16)b[1];
  v[6] = (__bf16)b[2]; v[7] = (__bf16)b[3];
  return v;
}

// ---------------- grouped GEMM: A bf16 gload_lds, B fp32 fused-cvt ----------------
__global__ __launch_bounds__(512, 2)
void moe_gemm_fusedW2(const __bf16* __restrict__ xb,
                      const float* __restrict__ w,
                      const int* __restrict__ ef,
                      float* __restrict__ out) {
  __shared__ __attribute__((aligned(16))) char lds[2 * LDS_BUF];  // 128 KiB

  const int tid  = threadIdx.x;
  const int lane = tid & 63;
  const int wv   = tid >> 6;   // 0..7
  const int wm   = wv >> 2;    // 0..1 (M split, 128 rows)
  const int wn   = wv & 3;     // 0..3 (N split, 64 cols)
  const int fr   = lane & 15;
  const int kg   = lane >> 4;

  // T1: bijective XCD swizzle (640 % 8 == 0)
  const int b    = blockIdx.x;
  const int tile = (b & 7) * (MAXMT * NTN / 8) + (b >> 3);
  const int nt   = tile % NTN;
  const int mt   = tile / NTN;

  // m-tile -> (expert, row range); tokens contiguous per expert
  int cumT = 0, cumTok = 0;
  int e = -1, rowStart = 0, lastRow = 0;
  for (int i = 0; i < NE; ++i) {
    int f = ef[i];
    int t = (f + BM - 1) / BM;
    if (mt < cumT + t) {
      e = i;
      rowStart = cumTok + (mt - cumT) * BM;
      lastRow  = cumTok + f - 1;
      break;
    }
    cumT += t;
    cumTok += f;
  }
  if (e < 0) return;  // dead tile, uniform across block, before any barrier

  const float* wexp = w + (size_t)e * DOUT * DIN;
  const int ncol0 = nt * BN;

  // ---- A staging (R3-verified): granule g = 64 rows; wave covers rows
  // g*64 + wv*8 .. +7; source slot pre-applies the read involution.
  const int srow  = wv * 8 + (lane >> 3);
  const int sslot = (lane & 7) ^ (lane >> 3);
  const __bf16* aSrc[4];
#pragma unroll
  for (int j = 0; j < 4; ++j) {
    int ar = rowStart + j * 64 + srow;
    ar = ar > lastRow ? lastRow : ar;          // clamp ragged M (C guarded)
    aSrc[j] = xb + (size_t)ar * DIN + sslot * 8;
  }

  // ---- B reg-staging: thread covers W row brow = tid>>1, k-half kh = tid&1
  // (32 contiguous fp32 = 128 B per thread per K-tile).
  const int brow = tid >> 1;
  const int kh   = tid & 1;
  const float* bSrc = wexp + (size_t)(ncol0 + brow) * DIN + kh * 32;
  char* bDstBase = lds + BOFF;
  int bWrOff[4];
#pragma unroll
  for (int q = 0; q < 4; ++q)
    bWrOff[q] = lds_off(brow, (kh * 32 + q * 8) * 2);

#define STA(bufi, j, k0) gload_lds16(aSrc[j] + (k0), lds + (bufi)*LDS_BUF + (j)*GRAN + wv*1024)
#define LDA(bufi, r, cb) lds_rd(lds + (bufi)*LDS_BUF + lds_off((r), (cb)))
#define LDB(bufi, r, cb) lds_rd(lds + (bufi)*LDS_BUF + BOFF + lds_off((r), (cb)))

  f32x4 acc[8][4];
#pragma unroll
  for (int m = 0; m < 8; ++m)
#pragma unroll
    for (int n = 0; n < 4; ++n)
      acc[m][n] = f32x4{0.f, 0.f, 0.f, 0.f};

  f32x4 br[8];

  // ---- prologue ----
#pragma unroll
  for (int q = 0; q < 8; ++q)   // B(0) fp32
    br[q] = *reinterpret_cast<const f32x4*>(bSrc + q * 4);
  STA(0, 0, 0); STA(0, 1, 0); STA(0, 2, 0); STA(0, 3, 0);   // A(0)
  STA(1, 0, BK); STA(1, 2, BK);                              // A(1) g0,g2
  {  // cvt + write B(0) -> buf0 (auto-waits the br loads)
    char* d = bDstBase + 0 * LDS_BUF;
#pragma unroll
    for (int q = 0; q < 4; ++q)
      *reinterpret_cast<bf16x8*>(d + bWrOff[q]) = pack_bf16(br[2 * q], br[2 * q + 1]);
  }
#pragma unroll
  for (int q = 0; q < 8; ++q)   // B(1) fp32 (consumed at tile0.P1 — ample cover)
    br[q] = *reinterpret_cast<const f32x4*>(bSrc + (size_t)BK + q * 4);
  asm volatile("s_waitcnt lgkmcnt(0)" ::: "memory");  // B(0) writes drained
  asm volatile("s_waitcnt vmcnt(10)" ::: "memory");   // A(0) landed; A(1)g0g2 + br fly
  __builtin_amdgcn_s_barrier();

  for (int t = 0; t < NKT; ++t) {
    const int buf = t & 1;
    bf16x8 bfr[2][4];

    // ================= phase 0: acc rows 0..3 =================
    if (t + 1 < NKT) {              // A(t+1) g1,g3 (region read at t-1.P1, drained)
      STA(buf ^ 1, 1, (t + 1) * BK);
      STA(buf ^ 1, 3, (t + 1) * BK);
    }
    {
      bf16x8 a0[2][4];
#pragma unroll
      for (int kk = 0; kk < 2; ++kk) {
#pragma unroll
        for (int nn = 0; nn < 4; ++nn)
          bfr[kk][nn] = LDB(buf, wn * 64 + nn * 16 + fr, kk * 64 + kg * 16);
#pragma unroll
        for (int i = 0; i < 4; ++i)
          a0[kk][i] = LDA(buf, wm * 128 + i * 16 + fr, kk * 64 + kg * 16);
      }
      __builtin_amdgcn_s_barrier();
      asm volatile("s_waitcnt lgkmcnt(0)" ::: "memory");
      __builtin_amdgcn_s_setprio(1);
#pragma unroll
      for (int kk = 0; kk < 2; ++kk)
#pragma unroll
        for (int i = 0; i < 4; ++i)
#pragma unroll
          for (int nn = 0; nn < 4; ++nn)
            acc[i][nn] = mfma16(a0[kk][i], bfr[kk][nn], acc[i][nn]);
      __builtin_amdgcn_s_setprio(0);
      __builtin_amdgcn_s_barrier();
    }

    // ================= phase 1: acc rows 4..7 =================
    {
      if (t + 2 < NKT) {            // A(t+2) g0,g2 (granules consumed at P0)
        STA(buf, 0, (t + 2) * BK);
        STA(buf, 2, (t + 2) * BK);
      }
      if (t + 1 < NKT) {            // cvt + write B(t+1) -> buf^1 (auto-wait br)
        char* d = bDstBase + (buf ^ 1) * LDS_BUF;
#pragma unroll
        for (int q = 0; q < 4; ++q)
          *reinterpret_cast<bf16x8*>(d + bWrOff[q]) = pack_bf16(br[2 * q], br[2 * q + 1]);
      }
      if (t + 2 < NKT) {            // issue B(t+2) NOW -> consumed at t+1.P1
#pragma unroll                      // (full K-tile of latency cover, regs recycled)
        for (int q = 0; q < 8; ++q)
          br[q] = *reinterpret_cast<const f32x4*>(bSrc + (size_t)(t + 2) * BK + q * 4);
      }
      bf16x8 a1[2][4];
#pragma unroll
      for (int kk = 0; kk < 2; ++kk)
#pragma unroll
        for (int i = 0; i < 4; ++i)
          a1[kk][i] = LDA(buf, wm * 128 + (4 + i) * 16 + fr, kk * 64 + kg * 16);
      __builtin_amdgcn_s_barrier();
      asm volatile("s_waitcnt lgkmcnt(0)" ::: "memory");  // reads + B writes drained
      __builtin_amdgcn_s_setprio(1);
#pragma unroll
      for (int kk = 0; kk < 2; ++kk)
#pragma unroll
        for (int i = 0; i < 4; ++i)
#pragma unroll
          for (int nn = 0; nn < 4; ++nn)
            acc[4 + i][nn] = mfma16(a1[kk][i], bfr[kk][nn], acc[4 + i][nn]);
      __builtin_amdgcn_s_setprio(0);
      // counted wait (T4): drain A(t+1) g1,g3 (oldest); keep A(t+2) g0,g2 (2)
      // + br(t+2) (8) = 10 in flight.
      if (t + 1 < NKT) {
        if (t + 2 < NKT) { asm volatile("s_waitcnt vmcnt(10)" ::: "memory"); }
        else             { asm volatile("s_waitcnt vmcnt(0)" ::: "memory"); }
      }
      __builtin_amdgcn_s_barrier();
    }
  }

  // ---- epilogue: C/D layout col = lane&15, row = (lane>>4)*4 + j ----
  const int rq = (lane >> 4) * 4;
#pragma unroll
  for (int mm = 0; mm < 8; ++mm) {
#pragma unroll
    for (int j = 0; j < 4; ++j) {
      const int grow = rowStart + wm * 128 + mm * 16 + rq + j;
      if (grow <= lastRow) {
        float* op = out + (size_t)grow * DOUT + ncol0 + wn * 64;
#pragma unroll
        for (int nn = 0; nn < 4; ++nn)
          op[nn * 16 + fr] = acc[mm][nn][j];
      }
    }
  }
#undef STA
#undef LDA
#undef LDB
}

// ---------------- fallback: fused fp32-staging kernel (R1, verified) ----------------
__device__ __forceinline__ short8 cvt_bf16x8(f32x4 a, f32x4 b) {
  bf16x8 v;
  v[0] = (__bf16)a[0]; v[1] = (__bf16)a[1];
  v[2] = (__bf16)a[2]; v[3] = (__bf16)a[3];
  v[4] = (__bf16)b[0]; v[5] = (__bf16)b[1];
  v[6] = (__bf16)b[2]; v[7] = (__bf16)b[3];
  return __builtin_bit_cast(short8, v);
}

__global__ __launch_bounds__(256, 2)
void moe_grouped_gemm_f32(const float* __restrict__ x,
                          const float* __restrict__ w,
                          const int* __restrict__ ef,
                          float* __restrict__ out) {
  __shared__ float As[128 * 32];
  __shared__ float Bs[128 * 32];
  const int tid = threadIdx.x, lane = tid & 63, wv = tid >> 6;
  const int bid = blockIdx.x, nt = bid % 32, mt = bid / 32;
  int cumT = 0, cumTok = 0, e = -1, rowStart = 0, lastRow = 0;
  for (int i = 0; i < NE; ++i) {
    int f = ef[i], t = (f + 127) / 128;
    if (mt < cumT + t) { e = i; rowStart = cumTok + (mt - cumT) * 128; lastRow = cumTok + f - 1; break; }
    cumT += t; cumTok += f;
  }
  if (e < 0) return;
  const float* wexp = w + (size_t)e * DOUT * DIN;
  const int ncol0 = nt * 128;
  const int srow = lane >> 3, scol = (lane & 7) * 4;
  f32x4 acc[4][4];
#pragma unroll
  for (int m = 0; m < 4; ++m)
#pragma unroll
    for (int n = 0; n < 4; ++n) acc[m][n] = f32x4{0.f, 0.f, 0.f, 0.f};
  const int wr = (wv >> 1) * 64, wc = (wv & 1) * 64;
  for (int k0 = 0; k0 < DIN; k0 += 32) {
    __syncthreads();
#pragma unroll
    for (int i = 0; i < 4; ++i) {
      const int seg = i * 4 + wv;
      int arow = rowStart + seg * 8 + srow;
      arow = arow > lastRow ? lastRow : arow;
      gload_lds16(x + (size_t)arow * DIN + k0 + scol, &As[seg * 256]);
      const int brow = ncol0 + seg * 8 + srow;
      gload_lds16(wexp + (size_t)brow * DIN + k0 + scol, &Bs[seg * 256]);
    }
    __syncthreads();
    const int kb = (lane >> 4) * 8, fr = lane & 15;
    short8 afr[4], bfr[4];
#pragma unroll
    for (int m = 0; m < 4; ++m) {
      const f32x4* p = reinterpret_cast<const f32x4*>(&As[(wr + m * 16 + fr) * 32 + kb]);
      afr[m] = cvt_bf16x8(p[0], p[1]);
    }
#pragma unroll
    for (int n = 0; n < 4; ++n) {
      const f32x4* p = reinterpret_cast<const f32x4*>(&Bs[(wc + n * 16 + fr) * 32 + kb]);
      bfr[n] = cvt_bf16x8(p[0], p[1]);
    }
#pragma unroll
    for (int m = 0; m < 4; ++m)
#pragma unroll
      for (int n = 0; n < 4; ++n)
        acc[m][n] = __builtin_amdgcn_mfma_f32_16x16x32_bf16(afr[m], bfr[n], acc[m][n], 0, 0, 0);
  }
  const int fr = lane & 15, rq = (lane >> 4) * 4;
#pragma unroll
  for (int m = 0; m < 4; ++m)
#pragma unroll
    for (int j = 0; j < 4; ++j) {
      const int grow = rowStart + wr + m * 16 + rq + j;
      if (grow <= lastRow) {
        float* op = out + (size_t)grow * DOUT + ncol0 + wc;
#pragma unroll
        for (int n = 0; n < 4; ++n) op[n * 16 + fr] = acc[m][n][j];
      }
    }
}

extern "C" void kernel_launch(void* const* d_in, const int* in_sizes, int n_in,
                              void* d_out, int out_size, void* d_ws, size_t ws_size,
                              hipStream_t stream) {
  const float* x  = (const float*)d_in[0];
  const float* w  = (const float*)d_in[1];
  const int*   ef = (const int*)d_in[2];
  float* out = (float*)d_out;
  (void)in_sizes; (void)n_in; (void)out_size;

  const size_t nx = (size_t)NTOK * DIN;            // 16.8M elems
  const size_t need = nx * sizeof(__bf16);         // 32 MiB (x only)

  if (ws_size >= need) {
    __bf16* xb = (__bf16*)d_ws;
    {
      int n8 = (int)(nx / 8);
      int grid = (n8 + 255) / 256; if (grid > 2048) grid = 2048;
      cvt_f32_bf16<<<dim3(grid), dim3(256), 0, stream>>>(x, xb, n8);
    }
    moe_gemm_fusedW2<<<dim3(MAXMT * NTN), dim3(512), 0, stream>>>(xb, w, ef, out);
  } else {
    moe_grouped_gemm_f32<<<dim3((NTOK / 128 + NE) * 32), dim3(256), 0, stream>>>(x, w, ef, out);
  }
}

// Round 8
// 274.406 us; speedup vs baseline: 1.6033x; 1.3853x over previous
//
#include <hip/hip_runtime.h>

#define NE 8
#define NTOK 8192
#define DIN 2048
#define DOUT 4096

// ---- 256x256, BK=32, 8 waves (2M x 4N), fused-W via gload_lds fp32 ----
#define BM 256
#define BN 256
#define BK 32
#define NTN (DOUT / BN)          // 16 n-tiles
#define MAXMT (NTOK / BM + NE)   // 40 m-tiles -> 640 blocks (%8==0)
#define NKT (DIN / BK)           // 64 K-tiles
#define LDS_BUF 49152            // one buffer: A 16K (bf16) + B 32K (fp32)
#define BOFF 16384               // B offset inside a buffer
#define AUNIT 8192               // A unit = 128 token-rows x 32k x 2B
#define BGRAN 8192               // B granule = 64 w-rows x 32k x 4B

typedef __attribute__((ext_vector_type(4))) float f32x4;
typedef __attribute__((ext_vector_type(8))) short short8;
typedef __attribute__((ext_vector_type(8))) __bf16 bf16x8;

__device__ __forceinline__ void gload_lds16(const void* g, void* l) {
  __builtin_amdgcn_global_load_lds(
      (const __attribute__((address_space(1))) void*)g,
      (__attribute__((address_space(3))) void*)l,
      16, 0, 0);
}

// ---------------- fp32 -> bf16 conversion pass (x only, ~16 us) ----------------
__global__ void cvt_f32_bf16(const float* __restrict__ in,
                             __bf16* __restrict__ out, int n8) {
  const int stride = gridDim.x * blockDim.x;
  for (int i = blockIdx.x * blockDim.x + threadIdx.x; i < n8; i += stride) {
    const f32x4* p = reinterpret_cast<const f32x4*>(in + (size_t)i * 8);
    f32x4 a = p[0], b = p[1];
    bf16x8 v;
    v[0] = (__bf16)a[0]; v[1] = (__bf16)a[1];
    v[2] = (__bf16)a[2]; v[3] = (__bf16)a[3];
    v[4] = (__bf16)b[0]; v[5] = (__bf16)b[1];
    v[6] = (__bf16)b[2]; v[7] = (__bf16)b[3];
    *reinterpret_cast<bf16x8*>(out + (size_t)i * 8) = v;
  }
}

__device__ __forceinline__ bf16x8 lds_rd(const char* p) {
  return *reinterpret_cast<const bf16x8*>(p);
}

__device__ __forceinline__ f32x4 mfma16(bf16x8 a, bf16x8 b, f32x4 c) {
  return __builtin_amdgcn_mfma_f32_16x16x32_bf16(
      __builtin_bit_cast(short8, a), __builtin_bit_cast(short8, b), c, 0, 0, 0);
}

__device__ __forceinline__ bf16x8 pack_bf16(f32x4 a, f32x4 b) {
  bf16x8 v;
  v[0] = (__bf16)a[0]; v[1] = (__bf16)a[1];
  v[2] = (__bf16)a[2]; v[3] = (__bf16)a[3];
  v[4] = (__bf16)b[0]; v[5] = (__bf16)b[1];
  v[6] = (__bf16)b[2]; v[7] = (__bf16)b[3];
  return v;
}

// A layout (R4/R5-verified, 0 conflicts): token row r, k-group kg (8 bf16):
//   LDS row j = r>>1 (128B), 16B slot = ((r&1)*4 + kg) ^ (j&7)
__device__ __forceinline__ int lds_offA(int r, int kg) {
  const int j = r >> 1;
  const int slot = (((r & 1) << 2) + kg) ^ (j & 7);
  return j * 128 + slot * 16;
}

// B layout (R3-verified swizzle on 128B rows): granule-local row rp (0..63),
// byte-col cb (0..127): byte = rp*128 + (cb ^ ((rp&7)<<4))
__device__ __forceinline__ int lds_offB(int rp, int cb) {
  return rp * 128 + (cb ^ ((rp & 7) << 4));
}

// ---------------- grouped GEMM: A bf16 gload_lds, B fp32 gload_lds + reg-cvt ----
__global__ __launch_bounds__(512, 2)
void moe_gemm_fusedW3(const __bf16* __restrict__ xb,
                      const float* __restrict__ w,
                      const int* __restrict__ ef,
                      float* __restrict__ out) {
  __shared__ __attribute__((aligned(16))) char lds[2 * LDS_BUF];  // 96 KiB

  const int tid  = threadIdx.x;
  const int lane = tid & 63;
  const int wv   = tid >> 6;   // 0..7
  const int wm   = wv >> 2;    // 0..1 (M split, 128 rows)
  const int wn   = wv & 3;     // 0..3 (N split, 64 cols = B granule wn)
  const int fr   = lane & 15;
  const int kg   = lane >> 4;

  // T1: bijective XCD swizzle (640 % 8 == 0)
  const int b    = blockIdx.x;
  const int tile = (b & 7) * (MAXMT * NTN / 8) + (b >> 3);
  const int nt   = tile % NTN;
  const int mt   = tile / NTN;

  // m-tile -> (expert, row range); tokens contiguous per expert
  int cumT = 0, cumTok = 0;
  int e = -1, rowStart = 0, lastRow = 0;
  for (int i = 0; i < NE; ++i) {
    int f = ef[i];
    int t = (f + BM - 1) / BM;
    if (mt < cumT + t) {
      e = i;
      rowStart = cumTok + (mt - cumT) * BM;
      lastRow  = cumTok + f - 1;
      break;
    }
    cumT += t;
    cumTok += f;
  }
  if (e < 0) return;  // dead tile, uniform across block, before any barrier

  const float* wexp = w + (size_t)e * DOUT * DIN;
  const int ncol0 = nt * BN;

  // ---- A staging source (R4/R5-verified): lane covers dest wv*1024 + l*16;
  // sp = (l&7)^(l>>3); subrow = 2*(wv*8+(l>>3)) + (sp>>2); koff = (sp&3)*8 bf16.
  const int sp     = (lane & 7) ^ (lane >> 3);
  const int subrow = 2 * (wv * 8 + (lane >> 3)) + (sp >> 2);
  const int akoff  = (sp & 3) * 8;
  const __bf16* aSrc[2];
#pragma unroll
  for (int u = 0; u < 2; ++u) {
    int ar = rowStart + u * 128 + subrow;
    ar = ar > lastRow ? lastRow : ar;          // clamp ragged M (C guarded)
    aSrc[u] = xb + (size_t)ar * DIN + akoff;
  }

  // ---- B staging source (fp32, source pre-swizzled; LDS dest linear):
  // granule g rows g*64 + wv*8 + (l>>3); slot sp -> f32 offset sp*4.
  const float* bSrc[4];
#pragma unroll
  for (int g = 0; g < 4; ++g) {
    const int brow = ncol0 + g * 64 + wv * 8 + (lane >> 3);
    bSrc[g] = wexp + (size_t)brow * DIN + sp * 4;
  }

#define STA(bufi, u, k0) gload_lds16(aSrc[u] + (k0), lds + (bufi)*LDS_BUF + (u)*AUNIT + wv*1024)
#define STB(bufi, g, k0) gload_lds16(bSrc[g] + (k0), lds + (bufi)*LDS_BUF + BOFF + (g)*BGRAN + wv*1024)
#define LDA(bufi, r) lds_rd(lds + (bufi)*LDS_BUF + lds_offA((r), kg))
#define LDB32(bufi, rp, cb) (*reinterpret_cast<const f32x4*>(lds + (bufi)*LDS_BUF + BOFF + wn*BGRAN + lds_offB((rp), (cb))))

  f32x4 acc[8][4];
#pragma unroll
  for (int m = 0; m < 8; ++m)
#pragma unroll
    for (int n = 0; n < 4; ++n)
      acc[m][n] = f32x4{0.f, 0.f, 0.f, 0.f};

  // ---- prologue: tiles 0 and 1 fully staged (6 loads each) ----
  STB(0, 0, 0);  STB(0, 1, 0);  STB(0, 2, 0);  STB(0, 3, 0);
  STA(0, 0, 0);  STA(0, 1, 0);
  STB(1, 0, BK); STB(1, 1, BK); STB(1, 2, BK); STB(1, 3, BK);
  STA(1, 0, BK); STA(1, 1, BK);
  asm volatile("s_waitcnt vmcnt(6)" ::: "memory");  // tile 0 landed
  __builtin_amdgcn_s_barrier();

  for (int t = 0; t < NKT; ++t) {
    const int buf = t & 1;
    bf16x8 bfr[4];

    // ========== phase 0: B all (fp32->bf16 in reg) + A rows 0..63 ==========
    // stage A(t+1) -> buf^1 (A there last read at t-1.P1, lgkm+barrier sep.)
    if (t >= 1 && t + 1 < NKT) { STA(buf ^ 1, 0, (t + 1) * BK); STA(buf ^ 1, 1, (t + 1) * BK); }
    {
      bf16x8 a0[4];
#pragma unroll
      for (int nn = 0; nn < 4; ++nn) {
        const int rp = nn * 16 + fr;
        f32x4 lo = LDB32(buf, rp, kg * 32);
        f32x4 hi = LDB32(buf, rp, kg * 32 + 16);
        bfr[nn] = pack_bf16(lo, hi);
      }
#pragma unroll
      for (int i = 0; i < 4; ++i)
        a0[i] = LDA(buf, wm * 128 + i * 16 + fr);
      __builtin_amdgcn_s_barrier();
      asm volatile("s_waitcnt lgkmcnt(0)" ::: "memory");
      __builtin_amdgcn_s_setprio(1);
#pragma unroll
      for (int i = 0; i < 4; ++i)
#pragma unroll
        for (int nn = 0; nn < 4; ++nn)
          acc[i][nn] = mfma16(a0[i], bfr[nn], acc[i][nn]);
      __builtin_amdgcn_s_setprio(0);
      __builtin_amdgcn_s_barrier();
    }

    // ========== phase 1: A rows 64..127 of wave half ==========
    // stage B(t+2) -> buf (B of buf fully read at P0 pre-barrier, lgkm-drained)
    {
      if (t + 2 < NKT) {
        STB(buf, 0, (t + 2) * BK); STB(buf, 1, (t + 2) * BK);
        STB(buf, 2, (t + 2) * BK); STB(buf, 3, (t + 2) * BK);
      }
      bf16x8 a1[4];
#pragma unroll
      for (int i = 0; i < 4; ++i)
        a1[i] = LDA(buf, wm * 128 + (4 + i) * 16 + fr);
      __builtin_amdgcn_s_barrier();
      asm volatile("s_waitcnt lgkmcnt(0)" ::: "memory");
      __builtin_amdgcn_s_setprio(1);
#pragma unroll
      for (int i = 0; i < 4; ++i)
#pragma unroll
        for (int nn = 0; nn < 4; ++nn)
          acc[4 + i][nn] = mfma16(a1[i], bfr[nn], acc[4 + i][nn]);
      __builtin_amdgcn_s_setprio(0);
      // counted wait (T4): queue = [B(t+1)x4, A(t+1)x2, B(t+2)x4];
      // drain through A(t+1) so tile t+1 is complete; keep B(t+2) in flight.
      if (t + 1 < NKT) {
        if (t + 2 < NKT) { asm volatile("s_waitcnt vmcnt(4)" ::: "memory"); }
        else             { asm volatile("s_waitcnt vmcnt(0)" ::: "memory"); }
      }
      __builtin_amdgcn_s_barrier();
    }
  }

  // ---- epilogue: C/D layout col = lane&15, row = (lane>>4)*4 + j ----
  const int rq = (lane >> 4) * 4;
#pragma unroll
  for (int mm = 0; mm < 8; ++mm) {
#pragma unroll
    for (int j = 0; j < 4; ++j) {
      const int grow = rowStart + wm * 128 + mm * 16 + rq + j;
      if (grow <= lastRow) {
        float* op = out + (size_t)grow * DOUT + ncol0 + wn * 64;
#pragma unroll
        for (int nn = 0; nn < 4; ++nn)
          op[nn * 16 + fr] = acc[mm][nn][j];
      }
    }
  }
#undef STA
#undef STB
#undef LDA
#undef LDB32
}

// ---------------- fallback: fused fp32-staging kernel (R1, verified) ----------------
__device__ __forceinline__ short8 cvt_bf16x8(f32x4 a, f32x4 b) {
  bf16x8 v;
  v[0] = (__bf16)a[0]; v[1] = (__bf16)a[1];
  v[2] = (__bf16)a[2]; v[3] = (__bf16)a[3];
  v[4] = (__bf16)b[0]; v[5] = (__bf16)b[1];
  v[6] = (__bf16)b[2]; v[7] = (__bf16)b[3];
  return __builtin_bit_cast(short8, v);
}

__global__ __launch_bounds__(256, 2)
void moe_grouped_gemm_f32(const float* __restrict__ x,
                          const float* __restrict__ w,
                          const int* __restrict__ ef,
                          float* __restrict__ out) {
  __shared__ float As[128 * 32];
  __shared__ float Bs[128 * 32];
  const int tid = threadIdx.x, lane = tid & 63, wv = tid >> 6;
  const int bid = blockIdx.x, nt = bid % 32, mt = bid / 32;
  int cumT = 0, cumTok = 0, e = -1, rowStart = 0, lastRow = 0;
  for (int i = 0; i < NE; ++i) {
    int f = ef[i], t = (f + 127) / 128;
    if (mt < cumT + t) { e = i; rowStart = cumTok + (mt - cumT) * 128; lastRow = cumTok + f - 1; break; }
    cumT += t; cumTok += f;
  }
  if (e < 0) return;
  const float* wexp = w + (size_t)e * DOUT * DIN;
  const int ncol0 = nt * 128;
  const int srow = lane >> 3, scol = (lane & 7) * 4;
  f32x4 acc[4][4];
#pragma unroll
  for (int m = 0; m < 4; ++m)
#pragma unroll
    for (int n = 0; n < 4; ++n) acc[m][n] = f32x4{0.f, 0.f, 0.f, 0.f};
  const int wr = (wv >> 1) * 64, wc = (wv & 1) * 64;
  for (int k0 = 0; k0 < DIN; k0 += 32) {
    __syncthreads();
#pragma unroll
    for (int i = 0; i < 4; ++i) {
      const int seg = i * 4 + wv;
      int arow = rowStart + seg * 8 + srow;
      arow = arow > lastRow ? lastRow : arow;
      gload_lds16(x + (size_t)arow * DIN + k0 + scol, &As[seg * 256]);
      const int brow = ncol0 + seg * 8 + srow;
      gload_lds16(wexp + (size_t)brow * DIN + k0 + scol, &Bs[seg * 256]);
    }
    __syncthreads();
    const int kb = (lane >> 4) * 8, fr = lane & 15;
    short8 afr[4], bfr[4];
#pragma unroll
    for (int m = 0; m < 4; ++m) {
      const f32x4* p = reinterpret_cast<const f32x4*>(&As[(wr + m * 16 + fr) * 32 + kb]);
      afr[m] = cvt_bf16x8(p[0], p[1]);
    }
#pragma unroll
    for (int n = 0; n < 4; ++n) {
      const f32x4* p = reinterpret_cast<const f32x4*>(&Bs[(wc + n * 16 + fr) * 32 + kb]);
      bfr[n] = cvt_bf16x8(p[0], p[1]);
    }
#pragma unroll
    for (int m = 0; m < 4; ++m)
#pragma unroll
      for (int n = 0; n < 4; ++n)
        acc[m][n] = __builtin_amdgcn_mfma_f32_16x16x32_bf16(afr[m], bfr[n], acc[m][n], 0, 0, 0);
  }
  const int fr = lane & 15, rq = (lane >> 4) * 4;
#pragma unroll
  for (int m = 0; m < 4; ++m)
#pragma unroll
    for (int j = 0; j < 4; ++j) {
      const int grow = rowStart + wr + m * 16 + rq + j;
      if (grow <= lastRow) {
        float* op = out + (size_t)grow * DOUT + ncol0 + wc;
#pragma unroll
        for (int n = 0; n < 4; ++n) op[n * 16 + fr] = acc[m][n][j];
      }
    }
}

extern "C" void kernel_launch(void* const* d_in, const int* in_sizes, int n_in,
                              void* d_out, int out_size, void* d_ws, size_t ws_size,
                              hipStream_t stream) {
  const float* x  = (const float*)d_in[0];
  const float* w  = (const float*)d_in[1];
  const int*   ef = (const int*)d_in[2];
  float* out = (float*)d_out;
  (void)in_sizes; (void)n_in; (void)out_size;

  const size_t nx = (size_t)NTOK * DIN;            // 16.8M elems
  const size_t need = nx * sizeof(__bf16);         // 32 MiB (x only)

  if (ws_size >= need) {
    __bf16* xb = (__bf16*)d_ws;
    {
      int n8 = (int)(nx / 8);
      int grid = (n8 + 255) / 256; if (grid > 2048) grid = 2048;
      cvt_f32_bf16<<<dim3(grid), dim3(256), 0, stream>>>(x, xb, n8);
    }
    moe_gemm_fusedW3<<<dim3(MAXMT * NTN), dim3(512), 0, stream>>>(xb, w, ef, out);
  } else {
    moe_grouped_gemm_f32<<<dim3((NTOK / 128 + NE) * 32), dim3(256), 0, stream>>>(x, w, ef, out);
  }
}